// Round 16
// baseline (142.704 us; speedup 1.0000x reference)
//
#include <hip/hip_runtime.h>

// R16: DIAGNOSTIC round. k_main is exactly R13 (best, 43.5us harness).
// Added k_abl<PHASE> ablation dispatches (no global output, asm-sinked):
//   PHASE 0: A-frags + tile staging + barrier
//   PHASE 1: + MFMA conv loop
//   PHASE 2: + softmax + fb + combine (stores sunk)
// Marginal rocprof durs locate the stall. Total dur_us is sacrificed.

constexpr int Nn = 8, Cc = 64, Hh = 192, Ww = 192;
constexpr int HW  = Hh * Ww;
constexpr int NKB = 18;
constexpr int BLOB_N = NKB * 64 * 8;
constexpr int TX = 32, TY = 8;
constexpr int SR = TY + 2, SC = TX + 2;
constexpr int NSTG = SR * SC * 8;
constexpr int FBS = 16;
constexpr int GX = Ww / TX, GY = Hh / TY;
constexpr int NWG = GX * GY * Nn;       // 1152
constexpr int CPX = NWG / 8;

typedef _Float16 f16x8 __attribute__((ext_vector_type(8)));
typedef float    f32x4 __attribute__((ext_vector_type(4)));
typedef __fp16   fp16x2 __attribute__((ext_vector_type(2)));

__device__ __forceinline__ unsigned pkh(float a, float b) {
    fp16x2 h = __builtin_amdgcn_cvt_pkrtz(a, b);
    union { fp16x2 h; unsigned u; } v; v.h = h;
    return v.u;
}
__device__ __forceinline__ unsigned short f2h(float f) {
    union { _Float16 h; unsigned short s; } v; v.h = (_Float16)f;
    return v.s;
}
__device__ __forceinline__ float h2f(unsigned short s) {
    union { unsigned short s; _Float16 h; } v; v.s = s;
    return (float)v.h;
}

__global__ __launch_bounds__(256)
void k_wprep(const float* __restrict__ cw, unsigned short* __restrict__ blob) {
    int idx = blockIdx.x * 256 + threadIdx.x;
    if (idx < BLOB_N) {
        int j  = idx & 7;
        int l  = (idx >> 3) & 63;
        int kb = idx >> 9;
        int k  = kb * 32 + ((l >> 4) << 3) + j;
        int m  = l & 15;
        int p  = k >> 6, c = k & 63;
        float v = (m < 9) ? cw[(m * Cc + c) * 9 + p] : 0.f;
        blob[idx] = f2h(v);
    }
}

// PHASE: 0=stage, 1=+mfma, 2=+epilogue(no store), 3=full (real kernel)
template<int PHASE>
__global__ __launch_bounds__(512, 4)
void k_body(const float* __restrict__ x, const unsigned short* __restrict__ blob,
            const float* __restrict__ gamma, float* __restrict__ out)
{
    __shared__ short xs[SR * SC * 64];
    __shared__ short fb[256 * FBS];

    const int b  = blockIdx.x;
    const int wt = (b & 7) * CPX + (b >> 3);
    const int bx = wt % GX;
    const int r2 = wt / GX;
    const int by = r2 % GY;
    const int n  = r2 / GY;

    const int tid  = threadIdx.x;
    const int lane = tid & 63, q = tid >> 6;
    const int w0 = bx * TX, h0 = by * TY;
    const float* __restrict__ xn = x + (size_t)n * Cc * HW;

    f16x8 af[NKB];
#pragma unroll
    for (int kb = 0; kb < NKB; ++kb)
        af[kb] = *(const f16x8*)(blob + (kb * 64 + lane) * 8);

#pragma unroll
    for (int i = 0; i < 6; ++i) {
        int idx = tid + i * 512;
        if (idx < NSTG) {
            int col  = idx % SC;
            int rest = idx / SC;
            int row  = rest % SR, cg = rest / SR;
            int gh = h0 + row - 1, gw = w0 + col - 1;
            bool ok = ((unsigned)gh < (unsigned)Hh) && ((unsigned)gw < (unsigned)Ww);
            const float* src = xn + (size_t)(cg * 8) * HW + gh * Ww + gw;
            float v[8];
#pragma unroll
            for (int j = 0; j < 8; ++j)
                v[j] = ok ? src[(size_t)j * HW] : 0.f;
            int widx = (row * SC + col) * 64 + ((cg ^ (col & 7)) << 3);
            *(int4*)&xs[widx] = make_int4(pkh(v[0], v[1]), pkh(v[2], v[3]),
                                          pkh(v[4], v[5]), pkh(v[6], v[7]));
        }
    }
    __syncthreads();

    if constexpr (PHASE == 0) {
        // keep staging + af live without doing compute
        float s0 = (float)*(const _Float16*)&xs[(tid * 67) % (SR * SC * 64)];
        float s1 = (float)af[tid % NKB][0];
        asm volatile("" :: "v"(s0), "v"(s1));
        return;
    }

    const int g8 = (lane >> 4) << 3;
    int cbase[3], chg[3][2];
#pragma unroll
    for (int dj = 0; dj < 3; ++dj) {
        int swz = (((lane & 15) + dj) & 7) << 3;
        chg[dj][0] = g8 ^ swz;
        chg[dj][1] = (32 | g8) ^ swz;
        cbase[dj]  = (q * SC + (lane & 15) + dj) * 64;
    }

    f32x4 z = {0.f, 0.f, 0.f, 0.f};
    f32x4 acc0 = z, acc1 = z;
#pragma unroll
    for (int kb = 0; kb < NKB; ++kb) {
        const int p = kb >> 1, di = p / 3, dj = p % 3, ch = kb & 1;
        const int a0 = cbase[dj] + di * (SC * 64) + chg[dj][ch];
        f16x8 b0 = *(const f16x8*)&xs[a0];
        f16x8 b1 = *(const f16x8*)&xs[a0 + 16 * 64];
        acc0 = __builtin_amdgcn_mfma_f32_16x16x32_f16(af[kb], b0, acc0, 0, 0, 0);
        acc1 = __builtin_amdgcn_mfma_f32_16x16x32_f16(af[kb], b1, acc1, 0, 0, 0);
    }

    if constexpr (PHASE == 1) {
        asm volatile("" :: "v"(acc0[0]), "v"(acc0[1]), "v"(acc0[2]), "v"(acc0[3]),
                          "v"(acc1[0]), "v"(acc1[1]), "v"(acc1[2]), "v"(acc1[3]));
        return;
    }

    const float g0 = gamma[0];
    const int gidx = lane >> 4;
    const int k0 = gidx * 4;
    const float NEG = -3.0e38f;

    f32x4 accs[2] = {acc0, acc1};
#pragma unroll
    for (int mt = 0; mt < 2; ++mt) {
        float a0 = accs[mt][0], a1 = accs[mt][1], a2 = accs[mt][2], a3 = accs[mt][3];
        float m0 = (gidx < 3) ? a0 : NEG;
        float m1 = (gidx < 2) ? a1 : NEG;
        float m2 = (gidx < 2) ? a2 : NEG;
        float m3 = (gidx < 2) ? a3 : NEG;
        float m = fmaxf(fmaxf(m0, m1), fmaxf(m2, m3));
        m = fmaxf(m, __shfl_xor(m, 16));
        m = fmaxf(m, __shfl_xor(m, 32));
        float e0 = (gidx < 3) ? __expf(a0 - m) : 0.f;
        float e1 = (gidx < 2) ? __expf(a1 - m) : 0.f;
        float e2 = (gidx < 2) ? __expf(a2 - m) : 0.f;
        float e3 = (gidx < 2) ? __expf(a3 - m) : 0.f;
        float s = (e0 + e1) + (e2 + e3);
        s += __shfl_xor(s, 16);
        s += __shfl_xor(s, 32);
        const float gs = g0 / s;
        const int px = q * 32 + mt * 16 + (lane & 15);
        if (gidx < 2) {
            *(unsigned*)&fb[px * FBS + k0]     = pkh(e0 * gs, e1 * gs);
            *(unsigned*)&fb[px * FBS + k0 + 2] = pkh(e2 * gs, e3 * gs);
        } else if (gidx == 2) {
            fb[px * FBS + 8] = f2h(e0 * gs);
        }
    }

    const int p0  = 2 * (lane & 15);
    const int cgA = lane >> 4;

    float fA[9], fB[9];
    {
        const int pxA = q * 32 + p0;
        union { int4 i; f16x8 h; } ca; ca.i = *(const int4*)&fb[pxA * FBS];
        union { int4 i; f16x8 h; } cb; cb.i = *(const int4*)&fb[(pxA + 1) * FBS];
#pragma unroll
        for (int k = 0; k < 8; ++k) { fA[k] = (float)ca.h[k]; fB[k] = (float)cb.h[k]; }
        fA[8] = h2f((unsigned short)fb[pxA * FBS + 8]);
        fB[8] = h2f((unsigned short)fb[(pxA + 1) * FBS + 8]);
    }

    float* outp = out + (size_t)n * Cc * HW + (size_t)(h0 + q) * Ww + (w0 + p0);

#pragma unroll
    for (int cgi = 0; cgi < 2; ++cgi) {
        const int cg = cgA + cgi * 4;
        float acc0c[8], acc1c[8], cen0[8], cen1[8];
#pragma unroll
        for (int j = 0; j < 8; ++j) { acc0c[j] = 0.f; acc1c[j] = 0.f; }
#pragma unroll
        for (int di = 0; di < 3; ++di) {
#pragma unroll
            for (int cc = 0; cc < 4; ++cc) {
                const int col = p0 + cc;
                const int addr = ((q + di) * SC + col) * 64
                               + ((cg ^ (col & 7)) << 3);
                union { int4 i; f16x8 h; } cv; cv.i = *(const int4*)&xs[addr];
#pragma unroll
                for (int j = 0; j < 8; ++j) {
                    float v = (float)cv.h[j];
                    if (cc < 3)  acc0c[j] = fmaf(fA[di * 3 + cc],     v, acc0c[j]);
                    if (cc >= 1) acc1c[j] = fmaf(fB[di * 3 + cc - 1], v, acc1c[j]);
                    if (di == 1 && cc == 1) cen0[j] = v;
                    if (di == 1 && cc == 2) cen1[j] = v;
                }
            }
        }
#pragma unroll
        for (int j = 0; j < 8; ++j) {
            float2 o = make_float2(acc0c[j] + cen0[j], acc1c[j] + cen1[j]);
            if constexpr (PHASE == 2) {
                asm volatile("" :: "v"(o.x), "v"(o.y));
            } else {
                *(float2*)&outp[(size_t)(cg * 8 + j) * HW] = o;
            }
        }
    }
}

extern "C" void kernel_launch(void* const* d_in, const int* in_sizes, int n_in,
                              void* d_out, int out_size, void* d_ws, size_t ws_size,
                              hipStream_t stream) {
    const float* x  = (const float*)d_in[0];
    const float* cw = (const float*)d_in[1];
    const float* gm = (const float*)d_in[2];
    float* out = (float*)d_out;
    unsigned short* blob = (unsigned short*)d_ws;

    k_wprep<<<dim3((BLOB_N + 255) / 256), dim3(256), 0, stream>>>(cw, blob);
    // the real kernel (R13-identical path, PHASE=3)
    k_body<3><<<dim3(NWG), dim3(512), 0, stream>>>(x, blob, gm, out);
    // ablation dispatches: no global output, rocprof rows are the product
    k_body<0><<<dim3(NWG), dim3(512), 0, stream>>>(x, blob, gm, out);
    k_body<1><<<dim3(NWG), dim3(512), 0, stream>>>(x, blob, gm, out);
    k_body<2><<<dim3(NWG), dim3(512), 0, stream>>>(x, blob, gm, out);
}

// Round 17
// 40.285 us; speedup vs baseline: 3.5424x; 3.5424x over previous
//
#include <hip/hip_runtime.h>

// DynamicWeights, fused MFMA kernel. R17 = R13 structure with a HALVED tile:
// 32x4 px, 256 threads (4 waves), 30 KB LDS -> 5 blocks/CU resident and a
// 2304-block grid (9/CU = ~2 residency rounds) per Little's law. No cross-
// phase register holding (R14's spill trap avoided).
//  K0 k_wprep: weights -> MFMA A-fragment blob (f16), rows 9..15 zeroed.
//  K1 k_main: stage x-tile (f16, XOR-swizzled) in LDS; conv via
//     mfma_f32_16x16x32_f16 (wave q: pixel row q, 2 m-tiles); softmax via
//     shfl; wave-local fb (no 2nd barrier); tap-shared combine + residual.
// x: (8,64,192,192) f32, conv_w: (9,64,3,3) f32, gamma: (1,) f32

constexpr int Nn = 8, Cc = 64, Hh = 192, Ww = 192;
constexpr int HW  = Hh * Ww;
constexpr int NKB = 18;                 // K-blocks: 576/32
constexpr int BLOB_N = NKB * 64 * 8;    // 9216 f16
constexpr int TX = 32, TY = 4;          // pixel tile (128 px)
constexpr int SR = TY + 2, SC = TX + 2; // staged rows/cols: 6 x 34
constexpr int NSTG = SR * SC * 8;       // 1632 staging units (8ch each)
constexpr int FBS = 16;                 // fbuf stride (shorts) per pixel
constexpr int GX = Ww / TX, GY = Hh / TY;          // 6, 48
constexpr int NWG = GX * GY * Nn;                  // 2304 (% 8 == 0)
constexpr int CPX = NWG / 8;                       // 288 tiles per XCD chunk

typedef _Float16 f16x8 __attribute__((ext_vector_type(8)));
typedef float    f32x4 __attribute__((ext_vector_type(4)));
typedef __fp16   fp16x2 __attribute__((ext_vector_type(2)));

__device__ __forceinline__ unsigned pkh(float a, float b) {
    fp16x2 h = __builtin_amdgcn_cvt_pkrtz(a, b);
    union { fp16x2 h; unsigned u; } v; v.h = h;
    return v.u;
}
__device__ __forceinline__ unsigned short f2h(float f) {
    union { _Float16 h; unsigned short s; } v; v.h = (_Float16)f;
    return v.s;
}
__device__ __forceinline__ float h2f(unsigned short s) {
    union { unsigned short s; _Float16 h; } v; v.s = s;
    return (float)v.h;
}

// ---- K0: weight blob in A-fragment layout (validated R7-R16) ----
__global__ __launch_bounds__(256)
void k_wprep(const float* __restrict__ cw, unsigned short* __restrict__ blob) {
    int idx = blockIdx.x * 256 + threadIdx.x;
    if (idx < BLOB_N) {
        int j  = idx & 7;
        int l  = (idx >> 3) & 63;
        int kb = idx >> 9;
        int k  = kb * 32 + ((l >> 4) << 3) + j;
        int m  = l & 15;
        int p  = k >> 6, c = k & 63;
        float v = (m < 9) ? cw[(m * Cc + c) * 9 + p] : 0.f;
        blob[idx] = f2h(v);
    }
}

// ---- K1: fused conv + softmax + combine, 4 waves/block, ONE barrier ----
__global__ __launch_bounds__(256, 5)   // 5 blocks/CU (LDS-bound), VGPR cap ~102
void k_main(const float* __restrict__ x, const unsigned short* __restrict__ blob,
            const float* __restrict__ gamma, float* __restrict__ out)
{
    __shared__ short xs[SR * SC * 64];   // 26112 B, swizzled [row][col][ch], f16
    __shared__ short fb[128 * FBS];      // 4096 B: per-pixel 9 filter taps (f16)

    // XCD-aware bijective swizzle (2304 % 8 == 0)
    const int b  = blockIdx.x;
    const int wt = (b & 7) * CPX + (b >> 3);
    const int bx = wt % GX;
    const int r2 = wt / GX;
    const int by = r2 % GY;
    const int n  = r2 / GY;

    const int tid  = threadIdx.x;
    const int lane = tid & 63, q = tid >> 6;       // wave q: pixel row q (0..3)
    const int w0 = bx * TX, h0 = by * TY;
    const float* __restrict__ xn = x + (size_t)n * Cc * HW;

    // A-frag pointers (compiler rematerializes loads in-loop; L1-hot)
    f16x8 af[NKB];
#pragma unroll
    for (int kb = 0; kb < NKB; ++kb)
        af[kb] = *(const f16x8*)(blob + (kb * 64 + lane) * 8);

    // ---- stage tile: (col, row, cgrp) -> 8 ch per b128 write, XOR-swizzled ----
#pragma unroll
    for (int i = 0; i < 7; ++i) {
        int idx = tid + i * 256;
        if (idx < NSTG) {
            int col  = idx % SC;
            int rest = idx / SC;
            int row  = rest % SR, cg = rest / SR;
            int gh = h0 + row - 1, gw = w0 + col - 1;
            bool ok = ((unsigned)gh < (unsigned)Hh) && ((unsigned)gw < (unsigned)Ww);
            const float* src = xn + (size_t)(cg * 8) * HW + gh * Ww + gw;
            float v[8];
#pragma unroll
            for (int j = 0; j < 8; ++j)
                v[j] = ok ? src[(size_t)j * HW] : 0.f;
            int widx = (row * SC + col) * 64 + ((cg ^ (col & 7)) << 3);
            *(int4*)&xs[widx] = make_int4(pkh(v[0], v[1]), pkh(v[2], v[3]),
                                          pkh(v[4], v[5]), pkh(v[6], v[7]));
        }
    }
    __syncthreads();   // the ONLY barrier

    // ---- MFMA: wave q owns pixel row q; px-in-row = (lane&15) + 16*mt ----
    const int g8 = (lane >> 4) << 3;
    int cbase[3], chg[3][2];
#pragma unroll
    for (int dj = 0; dj < 3; ++dj) {
        int swz = (((lane & 15) + dj) & 7) << 3;
        chg[dj][0] = g8 ^ swz;
        chg[dj][1] = (32 | g8) ^ swz;
        cbase[dj]  = (q * SC + (lane & 15) + dj) * 64;
    }

    f32x4 z = {0.f, 0.f, 0.f, 0.f};
    f32x4 acc0 = z, acc1 = z;

#pragma unroll
    for (int kb = 0; kb < NKB; ++kb) {
        const int p = kb >> 1, di = p / 3, dj = p % 3, ch = kb & 1;
        const int a0 = cbase[dj] + di * (SC * 64) + chg[dj][ch];
        f16x8 b0 = *(const f16x8*)&xs[a0];              // mt0: cols 0..15
        f16x8 b1 = *(const f16x8*)&xs[a0 + 16 * 64];    // mt1: cols 16..31
        acc0 = __builtin_amdgcn_mfma_f32_16x16x32_f16(af[kb], b0, acc0, 0, 0, 0);
        acc1 = __builtin_amdgcn_mfma_f32_16x16x32_f16(af[kb], b1, acc1, 0, 0, 0);
    }

    // ---- softmax (shfl over 16/32), filter -> fb[px][k] f16 (wave-local px) ----
    const float g0 = gamma[0];
    const int gidx = lane >> 4;
    const int k0 = gidx * 4;
    const float NEG = -3.0e38f;

    f32x4 accs[2] = {acc0, acc1};
#pragma unroll
    for (int mt = 0; mt < 2; ++mt) {
        float a0 = accs[mt][0], a1 = accs[mt][1], a2 = accs[mt][2], a3 = accs[mt][3];
        float m0 = (gidx < 3) ? a0 : NEG;
        float m1 = (gidx < 2) ? a1 : NEG;
        float m2 = (gidx < 2) ? a2 : NEG;
        float m3 = (gidx < 2) ? a3 : NEG;
        float m = fmaxf(fmaxf(m0, m1), fmaxf(m2, m3));
        m = fmaxf(m, __shfl_xor(m, 16));
        m = fmaxf(m, __shfl_xor(m, 32));
        float e0 = (gidx < 3) ? __expf(a0 - m) : 0.f;
        float e1 = (gidx < 2) ? __expf(a1 - m) : 0.f;
        float e2 = (gidx < 2) ? __expf(a2 - m) : 0.f;
        float e3 = (gidx < 2) ? __expf(a3 - m) : 0.f;
        float s = (e0 + e1) + (e2 + e3);
        s += __shfl_xor(s, 16);
        s += __shfl_xor(s, 32);
        const float gs = g0 / s;
        const int px = q * 32 + mt * 16 + (lane & 15);
        if (gidx < 2) {
            *(unsigned*)&fb[px * FBS + k0]     = pkh(e0 * gs, e1 * gs);
            *(unsigned*)&fb[px * FBS + k0 + 2] = pkh(e2 * gs, e3 * gs);
        } else if (gidx == 2) {
            fb[px * FBS + 8] = f2h(e0 * gs);
        }
    }
    // NO barrier: wave q reads back only row-q filters (lgkmcnt orders DS ops)

    // ---- combine + residual: lane owns adjacent px pair x 2 cgroups ----
    const int p0  = 2 * (lane & 15);           // pixel cols p0, p0+1 (0..30)
    const int cgA = lane >> 4;                  // cgroups cgA, cgA+4

    float fA[9], fB[9];
    {
        const int pxA = q * 32 + p0;
        union { int4 i; f16x8 h; } ca; ca.i = *(const int4*)&fb[pxA * FBS];
        union { int4 i; f16x8 h; } cb; cb.i = *(const int4*)&fb[(pxA + 1) * FBS];
#pragma unroll
        for (int k = 0; k < 8; ++k) { fA[k] = (float)ca.h[k]; fB[k] = (float)cb.h[k]; }
        fA[8] = h2f((unsigned short)fb[pxA * FBS + 8]);
        fB[8] = h2f((unsigned short)fb[(pxA + 1) * FBS + 8]);
    }

    float* outp = out + (size_t)n * Cc * HW + (size_t)(h0 + q) * Ww + (w0 + p0);

#pragma unroll
    for (int cgi = 0; cgi < 2; ++cgi) {
        const int cg = cgA + cgi * 4;
        float acc0c[8], acc1c[8], cen0[8], cen1[8];
#pragma unroll
        for (int j = 0; j < 8; ++j) { acc0c[j] = 0.f; acc1c[j] = 0.f; }
#pragma unroll
        for (int di = 0; di < 3; ++di) {
#pragma unroll
            for (int cc = 0; cc < 4; ++cc) {         // staged cols p0..p0+3
                const int col = p0 + cc;
                const int addr = ((q + di) * SC + col) * 64
                               + ((cg ^ (col & 7)) << 3);
                union { int4 i; f16x8 h; } cv; cv.i = *(const int4*)&xs[addr];
#pragma unroll
                for (int j = 0; j < 8; ++j) {
                    float v = (float)cv.h[j];          // fuses into v_fma_mix
                    if (cc < 3)  acc0c[j] = fmaf(fA[di * 3 + cc],     v, acc0c[j]);
                    if (cc >= 1) acc1c[j] = fmaf(fB[di * 3 + cc - 1], v, acc1c[j]);
                    if (di == 1 && cc == 1) cen0[j] = v;
                    if (di == 1 && cc == 2) cen1[j] = v;
                }
            }
        }
#pragma unroll
        for (int j = 0; j < 8; ++j) {
            float2 o = make_float2(acc0c[j] + cen0[j], acc1c[j] + cen1[j]);
            *(float2*)&outp[(size_t)(cg * 8 + j) * HW] = o;
        }
    }
}

extern "C" void kernel_launch(void* const* d_in, const int* in_sizes, int n_in,
                              void* d_out, int out_size, void* d_ws, size_t ws_size,
                              hipStream_t stream) {
    const float* x  = (const float*)d_in[0];
    const float* cw = (const float*)d_in[1];
    const float* gm = (const float*)d_in[2];
    float* out = (float*)d_out;
    unsigned short* blob = (unsigned short*)d_ws;   // 9216 f16 = 18 KB

    k_wprep<<<dim3((BLOB_N + 255) / 256), dim3(256), 0, stream>>>(cw, blob);
    k_main <<<dim3(NWG), dim3(256), 0, stream>>>(x, blob, gm, out);
}